// Round 1
// baseline (78.995 us; speedup 1.0000x reference)
//
#include <hip/hip_runtime.h>

constexpr int IMG_H = 128;
constexpr int IMG_W = 128;
constexpr int N_IMG = 4;
constexpr int CXCH = 3;
constexpr int CYCH = 21;
constexpr int RAD = 5;
constexpr int DIA = 11;                  // 2R+1
constexpr int TILE_H = 8;
constexpr int TILE_W = 16;
constexpr int PT_H = TILE_H + 2 * RAD;   // 18
constexpr int PT_W = TILE_W + 2 * RAD;   // 26
constexpr int NPIX = PT_H * PT_W;        // 468
constexpr int PSTR = 28;                 // padded floats/pixel: 2-way banks only
constexpr int NWAVES = 6;                // wave g owns window row di = g
constexpr int NTHREADS = NWAVES * 64;    // 384
constexpr int HW = IMG_H * IMG_W;

// Loss = (1/NHW) * sum_{n,p,delta} kval * (1 - y_p . y_{p+delta})
// kval = exp(-(di^2+dj^2)/72) * (0.9*exp(-50*|dx|^2) + 0.1)
// In-bounds pairs symmetric -> 60 half-window offsets, doubled.
// OOB (zero-pad) offsets folded analytically per pixel.
// R3 (this round): column-sharing register tiling. Each thread owns 2
// adjacent center pixels (held in regs); each wave owns one di row and
// sweeps neighbor columns once -> each 96B LDS column read feeds 2 pair
// terms. LDS b128/block: 720 -> 396 (1.82x). Pixel record padded to 28
// floats so lane stride 56 words == 24 mod 32 -> free 2-way aliasing.
__device__ __forceinline__ float pair_term(
    const float* __restrict__ yc, const float* __restrict__ xc,
    const float4 q0, const float4 q1, const float4 q2,
    const float4 q3, const float4 q4, const float4 q5, float e1) {
    float dot = q5.x * yc[20];
    dot += q0.x * yc[0]  + q0.y * yc[1]  + q0.z * yc[2]  + q0.w * yc[3];
    dot += q1.x * yc[4]  + q1.y * yc[5]  + q1.z * yc[6]  + q1.w * yc[7];
    dot += q2.x * yc[8]  + q2.y * yc[9]  + q2.z * yc[10] + q2.w * yc[11];
    dot += q3.x * yc[12] + q3.y * yc[13] + q3.z * yc[14] + q3.w * yc[15];
    dot += q4.x * yc[16] + q4.y * yc[17] + q4.z * yc[18] + q4.w * yc[19];
    float d0 = q5.y - xc[0], d1 = q5.z - xc[1], d2 = q5.w - xc[2];
    float s2 = d0 * d0 + d1 * d1 + d2 * d2;
    float kv = e1 * (0.9f * __expf(-50.0f * s2) + 0.1f);
    return kv * (1.0f - dot);
}

__global__ __launch_bounds__(NTHREADS, 3)
void gcrf_kernel(const float* __restrict__ x, const float* __restrict__ y,
                 float* __restrict__ out) {
    __shared__ __align__(16) float s[NPIX * PSTR];   // 52,416 B
    __shared__ float s_red[NWAVES];

    const int tid = threadIdx.x;
    const int n = blockIdx.z;
    const int h0 = blockIdx.y * TILE_H;
    const int w0 = blockIdx.x * TILE_W;

    const float* xb = x + (size_t)n * CXCH * HW;
    const float* yb = y + (size_t)n * CYCH * HW;

    // Stage padded tile; layout per pixel: [y0..y19 | y20 x0 x1 x2 | pad*4]
    for (int p = tid; p < NPIX; p += NTHREADS) {
        int ti = p / PT_W, tj = p - ti * PT_W;
        int gh = h0 + ti - RAD, gw = w0 + tj - RAD;
        bool inb = ((unsigned)gh < (unsigned)IMG_H) &&
                   ((unsigned)gw < (unsigned)IMG_W);
        int gofs = gh * IMG_W + gw;
        float v[CYCH];
        #pragma unroll
        for (int c = 0; c < CYCH; c++) v[c] = inb ? yb[c * HW + gofs] : 0.0f;
        float xv[CXCH];
        #pragma unroll
        for (int c = 0; c < CXCH; c++) xv[c] = inb ? xb[c * HW + gofs] : 0.0f;
        float* d = &s[p * PSTR];
        #pragma unroll
        for (int q = 0; q < 5; q++)
            *(float4*)&d[q * 4] = make_float4(v[q * 4 + 0], v[q * 4 + 1],
                                              v[q * 4 + 2], v[q * 4 + 3]);
        *(float4*)&d[20] = make_float4(v[20], xv[0], xv[1], xv[2]);
    }
    __syncthreads();

    const int g = tid >> 6;              // wave id == di row
    const int lane = tid & 63;
    const int row = lane >> 3;           // 0..7
    const int cs = lane & 7;             // 0..7 -> centers 2cs, 2cs+1
    const int h = h0 + row;
    const int wA = w0 + cs * 2;
    const int cp = (row + RAD) * PT_W + (cs * 2 + RAD);

    // centers in registers (2 pixels x (21 y + 3 x))
    float ycA[CYCH], ycB[CYCH], xcA[CXCH], xcB[CXCH];
    {
        const float* a = &s[cp * PSTR];
        const float* b = a + PSTR;
        #pragma unroll
        for (int q = 0; q < 5; q++) {
            float4 t = *(const float4*)&a[q * 4];
            ycA[q * 4 + 0] = t.x; ycA[q * 4 + 1] = t.y;
            ycA[q * 4 + 2] = t.z; ycA[q * 4 + 3] = t.w;
            float4 u = *(const float4*)&b[q * 4];
            ycB[q * 4 + 0] = u.x; ycB[q * 4 + 1] = u.y;
            ycB[q * 4 + 2] = u.z; ycB[q * 4 + 3] = u.w;
        }
        float4 t = *(const float4*)&a[20];
        ycA[20] = t.x; xcA[0] = t.y; xcA[1] = t.z; xcA[2] = t.w;
        float4 u = *(const float4*)&b[20];
        ycB[20] = u.x; xcB[0] = u.y; xcB[1] = u.z; xcB[2] = u.w;
    }

    const int di = g;
    const bool rowok = (h + di) < IMG_H;
    const float erow = __expf(-(float)(di * di) * (1.0f / 72.0f));
    // exp(-dj*dj/72), dj = 0..5 (indices fold after unroll)
    const float EDJ[6] = {1.0f, 0.98620695f, 0.94595945f,
                          0.88249690f, 0.80073744f, 0.70664826f};

    float acco = 0.0f;   // single-counted OOB fold
    float accp = 0.0f;   // half-window pair terms (doubled at the end)

    if (g == 0) {
        // ---- analytic OOB fold for this thread's 2 center pixels ----
        #pragma unroll
        for (int i = 0; i < 2; i++) {
            int ww = wA + i;
            const float* xc = i ? xcB : xcA;
            int i0 = max(0, RAD - h), i1 = min(DIA - 1, IMG_H - 1 - h + RAD);
            int j0 = max(0, RAD - ww), j1 = min(DIA - 1, IMG_W - 1 - ww + RAD);
            int n_oob = DIA * DIA - (i1 - i0 + 1) * (j1 - j0 + 1);
            if (n_oob > 0) {
                float oxy = (float)(h * h + ww * ww) * (1.0f / 36.0f);
                float s2c = xc[0] * xc[0] + xc[1] * xc[1] + xc[2] * xc[2];
                float kvo = __expf(-0.5f * oxy) *
                            (0.9f * __expf(-50.0f * s2c) + 0.1f);
                acco += (float)n_oob * kvo;
            }
        }
        // ---- di = 0 half-row: dj = 1..5 -> cols j-5 in [1,6] ----
        #pragma unroll
        for (int j = 6; j < 12; j++) {
            const float* nb = &s[(cp + (j - 5)) * PSTR];
            float4 q0 = *(const float4*)&nb[0];
            float4 q1 = *(const float4*)&nb[4];
            float4 q2 = *(const float4*)&nb[8];
            float4 q3 = *(const float4*)&nb[12];
            float4 q4 = *(const float4*)&nb[16];
            float4 q5 = *(const float4*)&nb[20];
            int gc = wA + (j - 5);
            float f = ((unsigned)gc < (unsigned)IMG_W) ? 1.0f : 0.0f;
            if (j <= 10)
                accp += pair_term(ycA, xcA, q0, q1, q2, q3, q4, q5,
                                  f * EDJ[j - 5]);
            if (j >= 7)
                accp += pair_term(ycB, xcB, q0, q1, q2, q3, q4, q5,
                                  f * EDJ[j - 6]);
        }
    } else {
        // ---- full dj row for di = g: one column read feeds 2 terms ----
        #pragma unroll
        for (int j = 0; j < 12; j++) {
            const float* nb = &s[(cp + di * PT_W + (j - 5)) * PSTR];
            float4 q0 = *(const float4*)&nb[0];
            float4 q1 = *(const float4*)&nb[4];
            float4 q2 = *(const float4*)&nb[8];
            float4 q3 = *(const float4*)&nb[12];
            float4 q4 = *(const float4*)&nb[16];
            float4 q5 = *(const float4*)&nb[20];
            int gc = wA + (j - 5);
            float f = (rowok && (unsigned)gc < (unsigned)IMG_W) ? erow : 0.0f;
            if (j <= 10) {               // center A: dj = j-5 in [-5,5]
                int a = j >= 5 ? j - 5 : 5 - j;
                accp += pair_term(ycA, xcA, q0, q1, q2, q3, q4, q5, f * EDJ[a]);
            }
            if (j >= 1) {                // center B: dj = j-6 in [-5,5]
                int a = j >= 6 ? j - 6 : 6 - j;
                accp += pair_term(ycB, xcB, q0, q1, q2, q3, q4, q5, f * EDJ[a]);
            }
        }
    }

    float total = acco + 2.0f * accp;

    // block reduce -> one atomic per block
    #pragma unroll
    for (int sft = 32; sft > 0; sft >>= 1)
        total += __shfl_down(total, sft, 64);
    if (lane == 0) s_red[g] = total;
    __syncthreads();
    if (tid == 0) {
        float bs = 0.0f;
        #pragma unroll
        for (int wv = 0; wv < NWAVES; wv++) bs += s_red[wv];
        atomicAdd(out, bs * (1.0f / (float)(N_IMG * HW)));
    }
}

extern "C" void kernel_launch(void* const* d_in, const int* in_sizes, int n_in,
                              void* d_out, int out_size, void* d_ws, size_t ws_size,
                              hipStream_t stream) {
    const float* x = (const float*)d_in[0];
    const float* y = (const float*)d_in[1];
    float* out = (float*)d_out;
    hipMemsetAsync(out, 0, sizeof(float), stream);
    dim3 grid(IMG_W / TILE_W, IMG_H / TILE_H, N_IMG);  // (8,16,4) = 512 blocks
    gcrf_kernel<<<grid, NTHREADS, 0, stream>>>(x, y, out);
}